// Round 1
// 198.420 us; speedup vs baseline: 1.0172x; 1.0172x over previous
//
#include <hip/hip_runtime.h>
#include <hip/hip_bf16.h>

// SchNet CFConv, MI355X gfx950 — round 4: offload f2out to MFMA GEMM kernel,
// LDS-staged neighbor gather (T14 split), single-barrier cfconv, direct-global
// dRe A-fragments (no s_dre staging pass).
//
// d_ws layout (unsigned short elements):
//   [0      .. 4096  )  W1T  bf16 [128 f][32 gpad]   (transposed, g>=25 zero)
//   [4096   .. 20480 )  W2T  bf16 [128 h][128 j]     (transposed)
//   [20480  .. 36864 )  WiT  bf16 [128 f][128 i]     (transposed)
//   [36864  .. 53248 )  WoT  bf16 [128 o][128 f]     (transposed Wf2o)
//   [53248  .. +1.28M)  yfeatb bf16 [10000][128]     (x @ W_in2f, L2-resident)
// Total 2.67 MB (round-2 proved >=5.12 MB available).
//
// cfconv: 1 atom/block, 256 thr (4 waves), wave w owns N-tiles {2w,2w+1}.
//   prologue: issue nbr-row loads (3x bf16x8/thread) + all W1T/W2T fragments
//   stage1: H = ssp(dRe[48x32] @ W1 + b1) -> LDS bf16 [48][136]
//           (A-frags read straight from global dRe; q==3 handles g=24 tail)
//   stage: write gathered rows -> s_yf [48][136]  (latency hidden under stage1)
//   ONE __syncthreads()
//   stage2: A2 = H @ W2 (+b2 epilogue), B-frags preloaded in regs
//   gather: y[h] = sum_k cm[k]*(A2[k][h]+b2[h])*s_yf[k][h], imm-offset ds reads,
//           shfl-reduce, q==0 writes f32 y straight into `out` buffer
// f2out_mfma: out = ssp(y @ Wf2o + b) in place on `out` (each wave reads only
//   the 16 rows it later writes — no hazard), in2f-shaped MFMA GEMM.

#define NA 10000
#define NK 48
#define NF 128
#define HP  136   // H    LDS row pad (bf16): 272 B rows -> 2-way (free)
#define YFP 136   // s_yf LDS row pad (bf16): 272 B rows -> 2-way (free)

typedef __bf16 bf16x8 __attribute__((ext_vector_type(8)));
typedef float  f32x4  __attribute__((ext_vector_type(4)));

__device__ __forceinline__ unsigned short f2bs(float x) {
    return __builtin_bit_cast(unsigned short, (__bf16)x);
}
__device__ __forceinline__ float bs2f(unsigned short u) {
    return (float)__builtin_bit_cast(__bf16, u);
}
__device__ __forceinline__ float sspf(float v) {
    return fmaxf(v, 0.0f) + __logf(1.0f + __expf(-fabsf(v))) - 0.69314718056f;
}

// ---- setup: transpose-convert weights to bf16 in d_ws ----
__global__ __launch_bounds__(256) void prep_weights(
    const float* __restrict__ W1,
    const float* __restrict__ W2,
    const float* __restrict__ Wi,
    const float* __restrict__ Wo,
    unsigned short* __restrict__ wsb)
{
    int i = blockIdx.x * 256 + threadIdx.x;
    if (i < 4096) {                       // W1T[f][g], g padded to 32
        int f = i >> 5, g = i & 31;
        wsb[i] = (g < 25) ? f2bs(W1[g * NF + f]) : (unsigned short)0;
    } else if (i < 20480) {               // W2T[h][j]
        int j = i - 4096; int h = j >> 7, k = j & 127;
        wsb[i] = f2bs(W2[k * NF + h]);
    } else if (i < 36864) {               // WiT[f][i]
        int j = i - 20480; int f = j >> 7, k = j & 127;
        wsb[i] = f2bs(Wi[k * NF + f]);
    } else if (i < 53248) {               // WoT[o][f]
        int j = i - 36864; int f = j >> 7, k = j & 127;
        wsb[i] = f2bs(Wo[k * NF + f]);
    }
}

// ---- in2f: yfeatb = bf16( x @ W_in2f ), MFMA, 64 rows/block ----
__global__ __launch_bounds__(256) void in2f_mfma(
    const float* __restrict__ x,
    const unsigned short* __restrict__ WiT,
    unsigned short* __restrict__ yfeatb)
{
    const int tid = threadIdx.x;
    const int w = tid >> 6;
    const int lane = tid & 63;
    const int r = lane & 15;
    const int q = lane >> 4;
    const int m0 = blockIdx.x * 64 + w * 16;
    const int row = m0 + r;
    const bool rv = (row < NA);

    f32x4 acc[8];
    #pragma unroll
    for (int nt = 0; nt < 8; ++nt) { acc[nt][0]=0.f; acc[nt][1]=0.f; acc[nt][2]=0.f; acc[nt][3]=0.f; }

    #pragma unroll
    for (int ks = 0; ks < 4; ++ks) {
        bf16x8 a;
        if (rv) {
            const float4* xp = (const float4*)(x + (size_t)row * NF + ks * 32 + q * 8);
            float4 v0 = xp[0], v1 = xp[1];
            a[0]=(__bf16)v0.x; a[1]=(__bf16)v0.y; a[2]=(__bf16)v0.z; a[3]=(__bf16)v0.w;
            a[4]=(__bf16)v1.x; a[5]=(__bf16)v1.y; a[6]=(__bf16)v1.z; a[7]=(__bf16)v1.w;
        } else {
            #pragma unroll
            for (int j = 0; j < 8; ++j) a[j] = (__bf16)0.0f;
        }
        #pragma unroll
        for (int nt = 0; nt < 8; ++nt) {
            bf16x8 b = *(const bf16x8*)(WiT + (nt * 16 + r) * NF + ks * 32 + q * 8);
            acc[nt] = __builtin_amdgcn_mfma_f32_16x16x32_bf16(a, b, acc[nt], 0, 0, 0);
        }
    }
    #pragma unroll
    for (int nt = 0; nt < 8; ++nt) {
        #pragma unroll
        for (int reg = 0; reg < 4; ++reg) {
            int orow = m0 + q * 4 + reg;
            if (orow < NA)
                yfeatb[(size_t)orow * NF + nt * 16 + r] = f2bs(acc[nt][reg]);
        }
    }
}

// ---- cfconv: MFMA filter net + LDS-staged gather/aggregate -> y (f32, in out) ----
__global__ __launch_bounds__(256) void cfconv_mfma(
    const float* __restrict__ dR,
    const float* __restrict__ dRe,
    const float* __restrict__ mask,
    const int*   __restrict__ nbr,
    const float* __restrict__ b1,
    const float* __restrict__ b2,
    const unsigned short* __restrict__ W1T,
    const unsigned short* __restrict__ W2T,
    const unsigned short* __restrict__ yfeatb,
    float* __restrict__ yout)
{
    __shared__ __align__(16) unsigned short s_H[NK * HP];    // 13056 B
    __shared__ __align__(16) unsigned short s_yf[NK * YFP];  // 13056 B
    __shared__ float s_cm[NK];

    const int tid = threadIdx.x;
    const int n = blockIdx.x;
    const int w = tid >> 6;
    const int lane = tid & 63;
    const int r = lane & 15;
    const int q = lane >> 4;
    const int nt0 = w * 2;        // this wave's two N-tiles

    // ---- issue neighbor-row gather loads first (LDS write deferred: T14) ----
    const int kb = tid >> 4;      // row within [0,16)
    const int sp = tid & 15;      // 16B slot within row
    const int nb0 = nbr[n * NK + kb] * NF;
    const int nb1 = nbr[n * NK + kb + 16] * NF;
    const int nb2 = nbr[n * NK + kb + 32] * NF;
    bf16x8 g0 = *(const bf16x8*)(yfeatb + nb0 + sp * 8);
    bf16x8 g1 = *(const bf16x8*)(yfeatb + nb1 + sp * 8);
    bf16x8 g2 = *(const bf16x8*)(yfeatb + nb2 + sp * 8);

    // ---- preload all B fragments (L2-resident weights) ----
    bf16x8 bfr0 = *(const bf16x8*)(W1T + ((nt0    ) * 16 + r) * 32 + q * 8);
    bf16x8 bfr1 = *(const bf16x8*)(W1T + ((nt0 + 1) * 16 + r) * 32 + q * 8);
    bf16x8 bw[2][4];
    #pragma unroll
    for (int t = 0; t < 2; ++t)
        #pragma unroll
        for (int ks = 0; ks < 4; ++ks)
            bw[t][ks] = *(const bf16x8*)(W2T + ((nt0 + t) * 16 + r) * NF + ks * 32 + q * 8);

    // ---- cutoff * mask ----
    if (tid < NK) {
        float d = dR[n * NK + tid];
        float m = mask[n * NK + tid];
        s_cm[tid] = (d <= 5.0f) ? m : 0.0f;
    }

    const float bias1a = b1[nt0 * 16 + r];
    const float bias1b = b1[nt0 * 16 + 16 + r];
    const float bias2a = b2[nt0 * 16 + r];
    const float bias2b = b2[nt0 * 16 + 16 + r];

    // ---- stage 1: H = ssp(dRe @ W1 + b1), A-frags direct from global ----
    const float* dre_n = dRe + (size_t)n * (NK * 25);
    #pragma unroll
    for (int mt = 0; mt < 3; ++mt) {
        bf16x8 a;
        if (q < 3) {
            float av[8];
            __builtin_memcpy(av, dre_n + (mt * 16 + r) * 25 + q * 8, 32);
            #pragma unroll
            for (int j = 0; j < 8; ++j) a[j] = (__bf16)av[j];
        } else {
            float v = dre_n[(mt * 16 + r) * 25 + 24];
            a[0] = (__bf16)v;
            #pragma unroll
            for (int j = 1; j < 8; ++j) a[j] = (__bf16)0.0f;
        }
        f32x4 zf; zf[0]=0.f; zf[1]=0.f; zf[2]=0.f; zf[3]=0.f;
        f32x4 h0v = __builtin_amdgcn_mfma_f32_16x16x32_bf16(a, bfr0, zf, 0, 0, 0);
        f32x4 h1v = __builtin_amdgcn_mfma_f32_16x16x32_bf16(a, bfr1, zf, 0, 0, 0);
        #pragma unroll
        for (int reg = 0; reg < 4; ++reg) {
            int k = mt * 16 + q * 4 + reg;
            s_H[k * HP + nt0 * 16 + r]      = f2bs(sspf(h0v[reg] + bias1a));
            s_H[k * HP + nt0 * 16 + 16 + r] = f2bs(sspf(h1v[reg] + bias1b));
        }
    }

    // ---- write gathered rows to LDS (global latency hidden under stage1) ----
    *(bf16x8*)(&s_yf[(kb     ) * YFP + sp * 8]) = g0;
    *(bf16x8*)(&s_yf[(kb + 16) * YFP + sp * 8]) = g1;
    *(bf16x8*)(&s_yf[(kb + 32) * YFP + sp * 8]) = g2;

    __syncthreads();   // the ONLY barrier

    // ---- stage 2: A2 = H @ W2 (bias in epilogue) ----
    f32x4 acc[3][2];
    #pragma unroll
    for (int mt = 0; mt < 3; ++mt)
        #pragma unroll
        for (int t = 0; t < 2; ++t) { acc[mt][t][0]=0.f; acc[mt][t][1]=0.f; acc[mt][t][2]=0.f; acc[mt][t][3]=0.f; }

    #pragma unroll
    for (int ks = 0; ks < 4; ++ks) {
        #pragma unroll
        for (int mt = 0; mt < 3; ++mt) {
            bf16x8 a = *(const bf16x8*)(&s_H[(mt * 16 + r) * HP + ks * 32 + q * 8]);
            acc[mt][0] = __builtin_amdgcn_mfma_f32_16x16x32_bf16(a, bw[0][ks], acc[mt][0], 0, 0, 0);
            acc[mt][1] = __builtin_amdgcn_mfma_f32_16x16x32_bf16(a, bw[1][ks], acc[mt][1], 0, 0, 0);
        }
    }

    // ---- gather + masked aggregation from LDS (imm-offset ds reads) ----
    float part0 = 0.f, part1 = 0.f;
    const int h0 = nt0 * 16 + r;
    #pragma unroll
    for (int mt = 0; mt < 3; ++mt) {
        #pragma unroll
        for (int reg = 0; reg < 4; ++reg) {
            int k = mt * 16 + q * 4 + reg;
            float cmk = s_cm[k];
            part0 += cmk * (acc[mt][0][reg] + bias2a) * bs2f(s_yf[k * YFP + h0]);
            part1 += cmk * (acc[mt][1][reg] + bias2b) * bs2f(s_yf[k * YFP + h0 + 16]);
        }
    }
    part0 += __shfl_xor(part0, 16);
    part0 += __shfl_xor(part0, 32);
    part1 += __shfl_xor(part1, 16);
    part1 += __shfl_xor(part1, 32);
    if (q == 0) {
        yout[(size_t)n * NF + h0]      = part0;
        yout[(size_t)n * NF + h0 + 16] = part1;
    }
}

// ---- f2out: out = ssp(y @ Wf2o + b), MFMA, IN PLACE on the out buffer ----
// Each wave reads exactly the 16 rows it later writes (loads complete before
// any store via acc data-dependence) -> no intra/inter-block hazard.
__global__ __launch_bounds__(256) void f2out_mfma(
    const unsigned short* __restrict__ WoT,
    const float* __restrict__ bo,
    float* io)
{
    const int tid = threadIdx.x;
    const int w = tid >> 6;
    const int lane = tid & 63;
    const int r = lane & 15;
    const int q = lane >> 4;
    const int m0 = blockIdx.x * 64 + w * 16;
    const int row = m0 + r;
    const bool rv = (row < NA);

    f32x4 acc[8];
    #pragma unroll
    for (int nt = 0; nt < 8; ++nt) { acc[nt][0]=0.f; acc[nt][1]=0.f; acc[nt][2]=0.f; acc[nt][3]=0.f; }

    #pragma unroll
    for (int ks = 0; ks < 4; ++ks) {
        bf16x8 a;
        if (rv) {
            const float4* yp = (const float4*)(io + (size_t)row * NF + ks * 32 + q * 8);
            float4 v0 = yp[0], v1 = yp[1];
            a[0]=(__bf16)v0.x; a[1]=(__bf16)v0.y; a[2]=(__bf16)v0.z; a[3]=(__bf16)v0.w;
            a[4]=(__bf16)v1.x; a[5]=(__bf16)v1.y; a[6]=(__bf16)v1.z; a[7]=(__bf16)v1.w;
        } else {
            #pragma unroll
            for (int j = 0; j < 8; ++j) a[j] = (__bf16)0.0f;
        }
        #pragma unroll
        for (int nt = 0; nt < 8; ++nt) {
            bf16x8 b = *(const bf16x8*)(WoT + (nt * 16 + r) * NF + ks * 32 + q * 8);
            acc[nt] = __builtin_amdgcn_mfma_f32_16x16x32_bf16(a, b, acc[nt], 0, 0, 0);
        }
    }
    #pragma unroll
    for (int nt = 0; nt < 8; ++nt) {
        float bia = bo[nt * 16 + r];
        #pragma unroll
        for (int reg = 0; reg < 4; ++reg) {
            int orow = m0 + q * 4 + reg;
            if (orow < NA)
                io[(size_t)orow * NF + nt * 16 + r] = sspf(acc[nt][reg] + bia);
        }
    }
}

extern "C" void kernel_launch(void* const* d_in, const int* in_sizes, int n_in,
                              void* d_out, int out_size, void* d_ws, size_t ws_size,
                              hipStream_t stream)
{
    const float* x    = (const float*)d_in[0];
    const float* dR   = (const float*)d_in[1];
    const float* dRe  = (const float*)d_in[2];
    const float* mask = (const float*)d_in[3];
    const int*   nbr  = (const int*)d_in[4];
    const float* W1   = (const float*)d_in[5];
    const float* b1   = (const float*)d_in[6];
    const float* W2   = (const float*)d_in[7];
    const float* b2   = (const float*)d_in[8];
    const float* Wi2f = (const float*)d_in[9];
    const float* Wf2o = (const float*)d_in[10];
    const float* bf2o = (const float*)d_in[11];
    float* out = (float*)d_out;

    unsigned short* wsb = (unsigned short*)d_ws;
    unsigned short* W1T    = wsb;            // 4096 elems
    unsigned short* W2T    = wsb + 4096;     // 16384 elems
    unsigned short* WiT    = wsb + 20480;    // 16384 elems
    unsigned short* WoT    = wsb + 36864;    // 16384 elems
    unsigned short* yfeatb = wsb + 53248;    // 1,280,000 elems

    prep_weights<<<208, 256, 0, stream>>>(W1, W2, Wi2f, Wf2o, wsb);
    in2f_mfma<<<157, 256, 0, stream>>>(x, WiT, yfeatb);
    cfconv_mfma<<<NA, 256, 0, stream>>>(dR, dRe, mask, nbr, b1, b2,
                                        W1T, W2T, yfeatb, out);
    f2out_mfma<<<157, 256, 0, stream>>>(WoT, bf2o, out);
}